// Round 21
// baseline (277.750 us; speedup 1.0000x reference)
//
#include <hip/hip_runtime.h>
#include <hip/hip_bf16.h>
#include <stdint.h>

// ============================================================================
// MoE Autoencoder (N=8192, D_IN=2048, H=1024, E=8).  f32 in / f32 out,
// bf16-tolerance (0.0625) => bf16 MFMA compute.
// Round 21: 3-deep pipeline in gemm8p (enc/mlp/dec).  These run at 1 block/CU
// (LDS 96KB) with no inter-block TLP; 2-deep gave each tile ~650cy to cover
// ~900cy HBM latency.  3 buffers (144KB), vmcnt(12), stage kt+3.
// moe (2 blocks/CU) unchanged.  prep pinned at ~50us (2 nulls) — left as is.
// ============================================================================

using bf16 = __hip_bfloat16;
typedef __bf16 bf16x8 __attribute__((ext_vector_type(8)));
typedef float f32x4 __attribute__((ext_vector_type(4)));

static constexpr int NROWS = 8192;
static constexpr int DIN   = 2048;
static constexpr int HD    = 1024;
static constexpr int NEXP  = 8;
static constexpr int MAX_TILES = 72;
static constexpr int MAXFLAG  = 512;
static constexpr int MAXFLAG2 = 128;
static constexpr int F1Z = 7;
static constexpr int CASTB = 2048;
static constexpr int TRB   = 1664;
#define GAPTHR  0.02f
#define GAPTHR2 1.0e-3

__device__ __forceinline__ uint16_t f2u(float f) {
  bf16 h = __float2bfloat16(f);
  uint16_t u; __builtin_memcpy(&u, &h, 2); return u;
}
__device__ __forceinline__ float u2f(uint16_t u) {
  uint32_t x = ((uint32_t)u) << 16;
  float f; __builtin_memcpy(&f, &x, 4); return f;
}

typedef const __attribute__((address_space(1))) void* gas_ptr;
typedef __attribute__((address_space(3))) void* las_ptr;
__device__ __forceinline__ void async16(void* lds, const void* g) {
  __builtin_amdgcn_global_load_lds((gas_ptr)g, (las_ptr)lds, 16, 0, 0);
}

// ----------------------------------------------------------------------------
// prep: ctrs zero + x f32->bf16 cast + 4 weight transposes, one launch.
// ----------------------------------------------------------------------------
__global__ __launch_bounds__(256)
void prep_kernel(const float* __restrict__ x, uint16_t* __restrict__ x_bf,
                 const float* __restrict__ encW, uint16_t* __restrict__ encWT,
                 const float* __restrict__ mlpW, uint16_t* __restrict__ mlpWT,
                 const float* __restrict__ decW, uint16_t* __restrict__ decWT,
                 const float* __restrict__ expW, uint16_t* __restrict__ expWT,
                 int* __restrict__ ctrs_i)
{
  __shared__ float tile[128 * 65];
  const int b = blockIdx.x;
  const int t = threadIdx.x;
  if (b == 0 && t < 64) ctrs_i[t] = 0;

  if (b < CASTB) {                        // ---- x cast, 16 elems/iter ----
    const int n16 = NROWS * DIN / 16;
    for (int i = b * 256 + t; i < n16; i += CASTB * 256) {
      const float* s = x + (size_t)i * 16;
      float4 v0 = *(const float4*)(s);
      float4 v1 = *(const float4*)(s + 4);
      float4 v2 = *(const float4*)(s + 8);
      float4 v3 = *(const float4*)(s + 12);
      uint16_t tmp[16];
      tmp[0]=f2u(v0.x);  tmp[1]=f2u(v0.y);  tmp[2]=f2u(v0.z);  tmp[3]=f2u(v0.w);
      tmp[4]=f2u(v1.x);  tmp[5]=f2u(v1.y);  tmp[6]=f2u(v1.z);  tmp[7]=f2u(v1.w);
      tmp[8]=f2u(v2.x);  tmp[9]=f2u(v2.y);  tmp[10]=f2u(v2.z); tmp[11]=f2u(v2.w);
      tmp[12]=f2u(v3.x); tmp[13]=f2u(v3.y); tmp[14]=f2u(v3.z); tmp[15]=f2u(v3.w);
      int4 p0, p1;
      __builtin_memcpy(&p0, tmp, 16);
      __builtin_memcpy(&p1, tmp + 8, 16);
      *(int4*)(x_bf + (size_t)i * 16)     = p0;
      *(int4*)(x_bf + (size_t)i * 16 + 8) = p1;
    }
    return;
  }
  // ---- transpose+cast: out[C][R] = bf16(in[R][C]), 128x64 tile ----
  const float* in; uint16_t* out; int R, C, bx, by;
  int q = b - CASTB;
  if (q < 256)       { in = encW; out = encWT; R = DIN; C = HD;  bx = q & 15; by = q >> 4; }
  else if (q < 384)  { q -= 256;  in = mlpW; out = mlpWT; R = HD; C = HD;  bx = q & 15; by = q >> 4; }
  else if (q < 640)  { q -= 384;  in = decW; out = decWT; R = HD; C = DIN; bx = q & 31; by = q >> 5; }
  else { q -= 640; const int z = q >> 7; q &= 127;
         in = expW + (size_t)z * HD * HD; out = expWT + (size_t)z * HD * HD;
         R = HD; C = HD; bx = q & 15; by = q >> 4; }
  const int C0 = bx * 64, R0 = by * 128;
  {
    const int cl = (t & 7) * 8;
    float4 v[4][2];
#pragma unroll
    for (int p = 0; p < 4; ++p) {
      const int r = p * 32 + (t >> 3);
      const float* src = in + (size_t)(R0 + r) * C + C0 + cl;
      v[p][0] = *(const float4*)(src);
      v[p][1] = *(const float4*)(src + 4);
    }
#pragma unroll
    for (int p = 0; p < 4; ++p) {
      const int r = p * 32 + (t >> 3);
      float* dst = &tile[r * 65 + cl];
      dst[0]=v[p][0].x; dst[1]=v[p][0].y; dst[2]=v[p][0].z; dst[3]=v[p][0].w;
      dst[4]=v[p][1].x; dst[5]=v[p][1].y; dst[6]=v[p][1].z; dst[7]=v[p][1].w;
    }
  }
  __syncthreads();
  {
    const int rl = (t & 15) * 8;
#pragma unroll
    for (int p = 0; p < 4; ++p) {
      const int oc = p * 16 + (t >> 4);
      uint16_t tmp[8];
#pragma unroll
      for (int j = 0; j < 8; ++j) tmp[j] = f2u(tile[(rl + j) * 65 + oc]);
      int4 v; __builtin_memcpy(&v, tmp, 16);
      *(int4*)(out + (size_t)(C0 + oc) * R + R0 + rl) = v;
    }
  }
}

// ----------------------------------------------------------------------------
// Pipelined 256x128 GEMM, BK=64, 8 waves (4M x 2N), 3-DEEP pipeline:
// 3 LDS buffers (144KB), vmcnt(12) counted wait, stage kt+3 during MFMA.
// MODE 0: enc  relu(acc+b) -> bf16;  MODE 2: mlp RMW;  MODE 3: dec f32 out.
// ----------------------------------------------------------------------------
template<int MODE>
__device__ __forceinline__
void gemm8p_body(const uint16_t* __restrict__ A, const uint16_t* __restrict__ BT,
                 uint16_t* __restrict__ C16, float* __restrict__ C32,
                 const float* __restrict__ biasf, const float* __restrict__ scale,
                 int M, int N, int K)
{
  constexpr int BM = 256, BN = 128, BK = 64;
  __shared__ uint16_t As[3][BM * BK];   // 3 x 32 KB
  __shared__ uint16_t Bs[3][BN * BK];   // 3 x 16 KB   (144 KB total)

  const int t = threadIdx.x;
  const int ntyg = gridDim.y;
  const int nwg  = gridDim.x * ntyg;
  const int hwf  = blockIdx.y * gridDim.x + blockIdx.x;
  const int swzb = (hwf & 7) * (nwg >> 3) + (hwf >> 3);
  const int mtile = swzb / ntyg;
  const int ntile = swzb % ntyg;

  const int trow = t >> 3;
  const int cbD  = (t & 7) * 16;
  const int cbS  = cbD ^ ((trow & 7) << 4);
  const char* aRow[4];
  const char* bRow[2];
#pragma unroll
  for (int c = 0; c < 4; ++c)
    aRow[c] = (const char*)A + ((size_t)(mtile * BM + c * 64 + trow) * K) * 2 + cbS;
#pragma unroll
  for (int c = 0; c < 2; ++c)
    bRow[c] = (const char*)BT + ((size_t)(ntile * BN + c * 64 + trow) * K) * 2 + cbS;

  auto stage = [&](int b, int kt) {
#pragma unroll
    for (int c = 0; c < 4; ++c)
      async16(&As[b][c * 4096 + t * 8], aRow[c] + (size_t)kt * 128);
#pragma unroll
    for (int c = 0; c < 2; ++c)
      async16(&Bs[b][c * 4096 + t * 8], bRow[c] + (size_t)kt * 128);
  };

  const int wid = t >> 6, lane = t & 63;
  const int wm = wid >> 1, wn = wid & 1;
  const int frow = lane & 15, hi = lane >> 4;

  f32x4 acc[4][4];
  const f32x4 zero = {0.f, 0.f, 0.f, 0.f};
#pragma unroll
  for (int i = 0; i < 4; ++i)
#pragma unroll
    for (int j = 0; j < 4; ++j) acc[i][j] = zero;

  auto ldfrag = [&](const uint16_t* base, int row, int kk) {
    const int cb = (kk * 64 + hi * 16) ^ ((row & 7) << 4);
    return *reinterpret_cast<const bf16x8*>(
        reinterpret_cast<const char*>(base) + row * 128 + cb);
  };

  const int nt = K >> 6;                  // >= 16 for all our shapes
  stage(0, 0);
  stage(1, 1);
  stage(2, 2);

  int b = 0;
  for (int kt = 0; kt < nt; ++kt) {
    asm volatile("s_waitcnt vmcnt(12)" ::: "memory");  // tile kt landed;
    __builtin_amdgcn_s_barrier();                      // kt+1,kt+2 in flight

    bf16x8 af[4][2], bfr[4][2];
#pragma unroll
    for (int mi = 0; mi < 4; ++mi)
#pragma unroll
      for (int kk = 0; kk < 2; ++kk)
        af[mi][kk] = ldfrag(As[b], wm * 64 + mi * 16 + frow, kk);
#pragma unroll
    for (int ni = 0; ni < 4; ++ni)
#pragma unroll
      for (int kk = 0; kk < 2; ++kk)
        bfr[ni][kk] = ldfrag(Bs[b], wn * 64 + ni * 16 + frow, kk);

    asm volatile("s_waitcnt lgkmcnt(0)" ::: "memory");
    __builtin_amdgcn_s_barrier();                      // buf[b] overwritable

    if (kt + 3 < nt) stage(b, kt + 3);                 // overlaps MFMA

    __builtin_amdgcn_s_setprio(1);
#pragma unroll
    for (int kk = 0; kk < 2; ++kk)
#pragma unroll
      for (int mi = 0; mi < 4; ++mi)
#pragma unroll
        for (int ni = 0; ni < 4; ++ni)
          acc[mi][ni] = __builtin_amdgcn_mfma_f32_16x16x32_bf16(
              af[mi][kk], bfr[ni][kk], acc[mi][ni], 0, 0, 0);
    __builtin_amdgcn_s_setprio(0);

    b = (b == 2) ? 0 : b + 1;
  }

  // epilogue — C/D layout: col = lane&15, row = hi*4 + j   [m89]
  const int nbase = ntile * BN + wn * 64;
  const int rbase = mtile * BM + wm * 64 + hi * 4;
  const int cbase = lane & 15;
#pragma unroll
  for (int mi = 0; mi < 4; ++mi) {
#pragma unroll
    for (int j = 0; j < 4; ++j) {
      const int gr = rbase + mi * 16 + j;
#pragma unroll
      for (int ni = 0; ni < 4; ++ni) {
        const int gc = nbase + ni * 16 + cbase;
        float v = acc[mi][ni][j] + biasf[gc];
        if constexpr (MODE == 0) {
          C16[(size_t)gr * N + gc] = f2u(fmaxf(v, 0.f));
        } else if constexpr (MODE == 2) {
          const float prev = u2f(C16[(size_t)gr * N + gc]);
          C16[(size_t)gr * N + gc] = f2u(prev + v * scale[gr]);
        } else {
          C32[(size_t)gr * N + gc] = v;
        }
      }
    }
  }
}

__global__ __launch_bounds__(512)
void gemm_enc(const uint16_t* A, const uint16_t* BT, uint16_t* C16,
              const float* biasf, int M, int N, int K) {
  gemm8p_body<0>(A, BT, C16, nullptr, biasf, nullptr, M, N, K);
}
__global__ __launch_bounds__(512)
void gemm_mlp(const uint16_t* A, const uint16_t* BT, uint16_t* C16,
              const float* biasf, const float* scale, int M, int N, int K) {
  gemm8p_body<2>(A, BT, C16, nullptr, biasf, scale, M, N, K);
}
__global__ __launch_bounds__(512)
void gemm_dec(const uint16_t* A, const uint16_t* BT, float* C32,
              const float* biasf, int M, int N, int K) {
  gemm8p_body<3>(A, BT, nullptr, C32, biasf, nullptr, M, N, K);
}

// ----------------------------------------------------------------------------
// moe GEMM: gathered 128x128 tiles with counted-vmcnt 2-deep pipeline (R17).
// ----------------------------------------------------------------------------
__global__ __launch_bounds__(256)
void gemm_moe(const uint16_t* __restrict__ A, const uint16_t* __restrict__ BT,
              uint16_t* __restrict__ C16, const float* __restrict__ biasf,
              const int* __restrict__ rowperm, const int* __restrict__ tinfo,
              const float* __restrict__ scale, int M, int N, int K)
{
  __shared__ uint16_t As[2][128 * 64];
  __shared__ uint16_t Bs[2][128 * 64];

  const int t = threadIdx.x;
  const int nty = gridDim.y;
  const int nwg = gridDim.x * nty;
  const int hwf = blockIdx.y * gridDim.x + blockIdx.x;
  const int swz = (hwf & 7) * (nwg >> 3) + (hwf >> 3);
  const int mtile = swz / nty;
  const int ntile = swz % nty;

  const int nt2 = tinfo[0];
  if (mtile >= nt2) return;
  const int e      = tinfo[1 + mtile * 3 + 0];
  const int row0   = tinfo[1 + mtile * 3 + 1];
  const int rowend = tinfo[1 + mtile * 3 + 2];

  const int trow = t >> 3;
  const int cbD  = (t & 7) * 16;
  const int cbS  = cbD ^ ((trow & 7) << 4);
  const char* asrc[4];
  const char* bsrc[4];
#pragma unroll
  for (int c = 0; c < 4; ++c) {
    const int r = c * 32 + trow;
    int pr = row0 + r;
    if (pr > rowend - 1) pr = rowend - 1;
    asrc[c] = (const char*)A + ((size_t)rowperm[pr] * K) * 2 + cbS;
    bsrc[c] = (const char*)BT + (((size_t)e * N + ntile * 128 + r) * K) * 2 + cbS;
  }

  auto stage = [&](int b, int kt) {
#pragma unroll
    for (int c = 0; c < 4; ++c) {
      async16(&As[b][c * 2048 + t * 8], asrc[c] + (size_t)kt * 128);
      async16(&Bs[b][c * 2048 + t * 8], bsrc[c] + (size_t)kt * 128);
    }
  };

  f32x4 acc[4][4];
  const f32x4 zero = {0.f, 0.f, 0.f, 0.f};
#pragma unroll
  for (int i = 0; i < 4; ++i)
#pragma unroll
    for (int j = 0; j < 4; ++j) acc[i][j] = zero;

  const int wid = t >> 6, lane = t & 63;
  const int wm = wid >> 1, wn = wid & 1;
  const int frow = lane & 15, hi = lane >> 4;

  auto ldfrag = [&](const uint16_t* base, int row, int kk) {
    const int cb = (kk * 64 + hi * 16) ^ ((row & 7) << 4);
    return *reinterpret_cast<const bf16x8*>(
        reinterpret_cast<const char*>(base) + row * 128 + cb);
  };

  const int nk = K >> 6;
  stage(0, 0);
  stage(1, 1);

  for (int kt = 0; kt < nk; ++kt) {
    const int b = kt & 1;
    asm volatile("s_waitcnt vmcnt(8)" ::: "memory");
    __builtin_amdgcn_s_barrier();

    bf16x8 af[4][2], bfr[4][2];
#pragma unroll
    for (int mi = 0; mi < 4; ++mi)
#pragma unroll
      for (int kk = 0; kk < 2; ++kk)
        af[mi][kk] = ldfrag(As[b], wm * 64 + mi * 16 + frow, kk);
#pragma unroll
    for (int ni = 0; ni < 4; ++ni)
#pragma unroll
      for (int kk = 0; kk < 2; ++kk)
        bfr[ni][kk] = ldfrag(Bs[b], wn * 64 + ni * 16 + frow, kk);

    asm volatile("s_waitcnt lgkmcnt(0)" ::: "memory");
    __builtin_amdgcn_s_barrier();

    if (kt + 2 < nk) stage(b, kt + 2);

    __builtin_amdgcn_s_setprio(1);
#pragma unroll
    for (int kk = 0; kk < 2; ++kk)
#pragma unroll
      for (int mi = 0; mi < 4; ++mi)
#pragma unroll
        for (int ni = 0; ni < 4; ++ni)
          acc[mi][ni] = __builtin_amdgcn_mfma_f32_16x16x32_bf16(
              af[mi][kk], bfr[ni][kk], acc[mi][ni], 0, 0, 0);
    __builtin_amdgcn_s_setprio(0);
  }

  const int nbase = ntile * 128 + wn * 64;
  const int rbase = wm * 64 + hi * 4;
  const int cbase = lane & 15;
#pragma unroll
  for (int mi = 0; mi < 4; ++mi) {
#pragma unroll
    for (int j = 0; j < 4; ++j) {
      const int pr = row0 + rbase + mi * 16 + j;
      if (pr < rowend) {
        const int orig = rowperm[pr];
        const float sc = scale[orig];
        uint16_t* dst = C16 + (size_t)orig * N;
#pragma unroll
        for (int ni = 0; ni < 4; ++ni) {
          const int gc = nbase + ni * 16 + cbase;
          dst[gc] = f2u((acc[mi][ni][j] + biasf[e * N + gc]) * sc);
        }
      }
    }
  }
}

// ----------------------------------------------------------------------------
// Gate from bf16 h — coalesced, no count atomic.
// ----------------------------------------------------------------------------
__global__ __launch_bounds__(256)
void gate_kernel(const uint16_t* __restrict__ hbf, const float* __restrict__ gW,
                 const float* __restrict__ cW, const float* __restrict__ cb,
                 int* __restrict__ eidx, float* __restrict__ s0,
                 float* __restrict__ c1, int* __restrict__ nflag,
                 int* __restrict__ flaglist)
{
  const int lane = threadIdx.x & 63;
  const int row  = blockIdx.x * 4 + (threadIdx.x >> 6);
  const uint16_t* hrow = hbf + (size_t)row * HD;
  float a[10];
#pragma unroll
  for (int i = 0; i < 10; ++i) a[i] = 0.f;
  for (int kk = 0; kk < HD / 64; ++kk) {
    const int k = kk * 64 + lane;
    const float hv = u2f(hrow[k]);
    float4 g0 = *(const float4*)(gW + (size_t)k * 8);
    float4 g1 = *(const float4*)(gW + (size_t)k * 8 + 4);
    a[0] += hv * g0.x; a[1] += hv * g0.y; a[2] += hv * g0.z; a[3] += hv * g0.w;
    a[4] += hv * g1.x; a[5] += hv * g1.y; a[6] += hv * g1.z; a[7] += hv * g1.w;
    float2 cv = *(const float2*)(cW + (size_t)k * 2);
    a[8] += hv * cv.x; a[9] += hv * cv.y;
  }
#pragma unroll
  for (int off = 32; off > 0; off >>= 1) {
#pragma unroll
    for (int i = 0; i < 10; ++i) a[i] += __shfl_xor(a[i], off);
  }
  if (lane == 0) {
    int best = 0; float bm = a[0];
#pragma unroll
    for (int e2 = 1; e2 < 8; ++e2) if (a[e2] > bm) { bm = a[e2]; best = e2; }
    float sec = -3.0e38f;
#pragma unroll
    for (int e2 = 0; e2 < 8; ++e2) if (e2 != best) sec = fmaxf(sec, a[e2]);
    float s = 0.f;
#pragma unroll
    for (int e2 = 0; e2 < 8; ++e2) s += expf(a[e2] - bm);
    const float p  = 1.f / s;
    const float l0 = a[8] + cb[0], l1 = a[9] + cb[1];
    const float mx = fmaxf(l0, l1);
    const float e0 = expf(l0 - mx), e1 = expf(l1 - mx);
    const float inv = 1.f / (e0 + e1);
    eidx[row] = best;
    s0[row]   = p * (e0 * inv);
    c1[row]   = e1 * inv;
    if (bm - sec < GAPTHR) {
      int fi = atomicAdd(nflag, 1);
      if (fi < MAXFLAG) flaglist[fi] = row;
    }
  }
}

// ----------------------------------------------------------------------------
// fixup1<T>
// ----------------------------------------------------------------------------
template<typename T>
__global__ __launch_bounds__(256)
void fixup1_kernel(const float* __restrict__ x, const float* __restrict__ encW,
                   const int* __restrict__ flaglist, const int* __restrict__ nflag,
                   T* __restrict__ zpart, int fstride, int maxflag)
{
  __shared__ float xs[8][128];
  __shared__ T red[8][4][64];
  int nf = *nflag; if (nf > maxflag) nf = maxflag;
  if (nf <= 0) return;
  const int rs = blockIdx.z;
  const int nb = (nf + 7) >> 3;
  if (rs >= nb) return;
  const int t  = threadIdx.x;
  const int jb = blockIdx.x, kb = blockIdx.y;
  const int tj = t & 63, tk = t >> 6;
  const int j  = jb * 64 + tj;
  const int k0 = kb * 128 + tk * 32;
  float w[32];
#pragma unroll
  for (int kk = 0; kk < 32; ++kk)
    w[kk] = encW[(size_t)(k0 + kk) * HD + j];

  for (int fb = rs; fb < nb; fb += F1Z) {
    __syncthreads();
    {
      const int r  = t >> 5;
      const int kc = (t & 31) * 4;
      int f = fb * 8 + r; if (f > nf - 1) f = nf - 1;
      const int row = flaglist[f];
      *(float4*)&xs[r][kc] =
          *(const float4*)&x[(size_t)row * DIN + kb * 128 + kc];
    }
    __syncthreads();
    T acc[8];
#pragma unroll
    for (int r = 0; r < 8; ++r) acc[r] = (T)0;
#pragma unroll
    for (int kq = 0; kq < 8; ++kq) {
      float4 xv[8];
#pragma unroll
      for (int r = 0; r < 8; ++r)
        xv[r] = *(const float4*)&xs[r][tk * 32 + kq * 4];
#pragma unroll
      for (int r = 0; r < 8; ++r) {
        acc[r] += (T)xv[r].x * (T)w[kq * 4 + 0];
        acc[r] += (T)xv[r].y * (T)w[kq * 4 + 1];
        acc[r] += (T)xv[r].z * (T)w[kq * 4 + 2];
        acc[r] += (T)xv[r].w * (T)w[kq * 4 + 3];
      }
    }
#pragma unroll
    for (int r = 0; r < 8; ++r) red[r][tk][tj] = acc[r];
    __syncthreads();
#pragma unroll
    for (int p = 0; p < 2; ++p) {
      const int idx = p * 256 + t;
      const int r = idx >> 6, jj = idx & 63;
      const int f = fb * 8 + r;
      if (f < nf)
        zpart[((size_t)kb * fstride + f) * HD + jb * 64 + jj] =
            (red[r][0][jj] + red[r][1][jj]) + (red[r][2][jj] + red[r][3][jj]);
    }
  }
}

// ----------------------------------------------------------------------------
// fixup2<STAGE,T>
// ----------------------------------------------------------------------------
template<int STAGE, typename T>
__global__ __launch_bounds__(256)
void fixup2_kernel(const T* __restrict__ zpart, const float* __restrict__ encB,
                   const float* __restrict__ gW, const float* __restrict__ cW,
                   const float* __restrict__ cb, const int* __restrict__ flaglist,
                   const int* __restrict__ nflag, int* __restrict__ eidx,
                   float* __restrict__ s0, float* __restrict__ c1,
                   int* __restrict__ nflag2, int* __restrict__ flaglist2,
                   int fstride, int maxflag)
{
  __shared__ double red[4][10];
  int nf = *nflag; if (nf > maxflag) nf = maxflag;
  const int t = threadIdx.x, lane = t & 63, w = t >> 6;
  for (int f = blockIdx.x; f < nf; f += 128) {
    const int row = flaglist[f];
    double part[10];
#pragma unroll
    for (int i = 0; i < 10; ++i) part[i] = 0.0;
    for (int jj = t; jj < HD; jj += 256) {
      double z = 0.0;
#pragma unroll
      for (int kb = 0; kb < 16; ++kb)
        z += (double)zpart[((size_t)kb * fstride + f) * HD + jj];
      double hj = z + (double)encB[jj];
      hj = hj > 0.0 ? hj : 0.0;
      const float* gr = gW + (size_t)jj * 8;
#pragma unroll
      for (int e2 = 0; e2 < 8; ++e2) part[e2] += hj * (double)gr[e2];
      part[8] += hj * (double)cW[jj * 2];
      part[9] += hj * (double)cW[jj * 2 + 1];
    }
#pragma unroll
    for (int off = 32; off > 0; off >>= 1)
#pragma unroll
      for (int i = 0; i < 10; ++i) part[i] += __shfl_xor(part[i], off);
    if (lane == 0)
#pragma unroll
      for (int i = 0; i < 10; ++i) red[w][i] = part[i];
    __syncthreads();
    if (t == 0) {
      double a[10];
#pragma unroll
      for (int i = 0; i < 10; ++i)
        a[i] = red[0][i] + red[1][i] + red[2][i] + red[3][i];
      int best = 0; double bm = a[0];
#pragma unroll
      for (int e2 = 1; e2 < 8; ++e2) if (a[e2] > bm) { bm = a[e2]; best = e2; }
      double sec = -1.0e300;
#pragma unroll
      for (int e2 = 0; e2 < 8; ++e2) if (e2 != best && a[e2] > sec) sec = a[e2];
      double s = 0.0;
#pragma unroll
      for (int e2 = 0; e2 < 8; ++e2) s += exp(a[e2] - bm);
      const double p  = 1.0 / s;
      const double l0 = a[8] + (double)cb[0], l1 = a[9] + (double)cb[1];
      const double mx = l0 > l1 ? l0 : l1;
      const double e0 = exp(l0 - mx), e1 = exp(l1 - mx);
      const double inv = 1.0 / (e0 + e1);
      eidx[row] = best;
      s0[row]   = (float)(p * e0 * inv);
      c1[row]   = (float)(e1 * inv);
      if constexpr (STAGE == 0) {
        if (bm - sec < GAPTHR2) {
          int fi = atomicAdd(nflag2, 1);
          if (fi < MAXFLAG2) flaglist2[fi] = row;
        }
      }
    }
    __syncthreads();
  }
}

// ----------------------------------------------------------------------------
// scan + scatter + count, single block (LDS histogram).
// ----------------------------------------------------------------------------
__global__ __launch_bounds__(1024)
void scan_scatter_kernel(const int* __restrict__ eidx,
                         int* __restrict__ tinfo, int* __restrict__ rowperm)
{
  __shared__ int scnt[NEXP];
  __shared__ int soffs[NEXP];
  __shared__ int scur[NEXP];
  const int t = threadIdx.x;
  if (t < NEXP) scnt[t] = 0;
  __syncthreads();
  for (int n = t; n < NROWS; n += 1024)
    atomicAdd(&scnt[eidx[n]], 1);
  __syncthreads();
  if (t == 0) {
    int off = 0, nt = 0;
    for (int e = 0; e < NEXP; ++e) {
      soffs[e] = off; scur[e] = 0;
      const int c = scnt[e];
      const int end = off + c;
      for (int r = 0; r < c; r += 128) {
        tinfo[1 + nt * 3 + 0] = e;
        tinfo[1 + nt * 3 + 1] = off + r;
        tinfo[1 + nt * 3 + 2] = end;
        ++nt;
      }
      off = end;
    }
    tinfo[0] = nt;
  }
  __syncthreads();
  for (int n = t; n < NROWS; n += 1024) {
    const int e = eidx[n];
    rowperm[soffs[e] + atomicAdd(&scur[e], 1)] = n;
  }
}

// ----------------------------------------------------------------------------
extern "C" void kernel_launch(void* const* d_in, const int* in_sizes, int n_in,
                              void* d_out, int out_size, void* d_ws, size_t ws_size,
                              hipStream_t stream) {
  (void)in_sizes; (void)n_in; (void)out_size;
  const float* x      = (const float*)d_in[0];
  const float* enc_W  = (const float*)d_in[1];
  const float* enc_b  = (const float*)d_in[2];
  const float* gate_W = (const float*)d_in[3];
  const float* exp_W  = (const float*)d_in[4];
  const float* exp_b  = (const float*)d_in[5];
  const float* mlp_W  = (const float*)d_in[6];
  const float* mlp_b  = (const float*)d_in[7];
  const float* coef_W = (const float*)d_in[8];
  const float* coef_b = (const float*)d_in[9];
  const float* dec_W  = (const float*)d_in[10];
  const float* dec_b  = (const float*)d_in[11];

  char* ws = (char*)d_ws;
  size_t off = 0;
  auto alloc = [&](size_t bytes) {
    char* p = ws + off;
    off += (bytes + 255) & ~(size_t)255;
    return p;
  };
  uint16_t* encWT  = (uint16_t*)alloc((size_t)DIN * HD * 2);
  uint16_t* mlpWT  = (uint16_t*)alloc((size_t)HD * HD * 2);
  uint16_t* decWT  = (uint16_t*)alloc((size_t)HD * DIN * 2);
  uint16_t* expWT  = (uint16_t*)alloc((size_t)NEXP * HD * HD * 2);
  uint16_t* h_bf   = (uint16_t*)alloc((size_t)NROWS * HD * 2);
  float*    zpart  = (float*)   alloc((size_t)16 * MAXFLAG * HD * 4);
  int*      eidx   = (int*)     alloc(NROWS * 4);
  float*    s0     = (float*)   alloc(NROWS * 4);
  float*    c1     = (float*)   alloc(NROWS * 4);
  int*      rowperm= (int*)     alloc(NROWS * 4);
  int*      flags  = (int*)     alloc(MAXFLAG * 4);
  int*      flags2 = (int*)     alloc(MAXFLAG2 * 4);
  char*     ctrs   = (char*)    alloc(256);
  int*      tinfo  = (int*)     alloc((1 + MAX_TILES * 3) * 4 + 64);
  uint16_t* x_bf   = (uint16_t*)zpart;   // lifetime-disjoint aliases (see R14)
  double*   zpartB = (double*)zpart;
  uint16_t* accout = (uint16_t*)zpart;
  int*      nflag  = (int*)(ctrs + 32);
  int*      nflag2 = (int*)(ctrs + 64);
  if (off > ws_size) return;

  const dim3 blk(256);
  prep_kernel<<<dim3(CASTB + TRB), blk, 0, stream>>>(
      x, x_bf, enc_W, encWT, mlp_W, mlpWT, dec_W, decWT, exp_W, expWT,
      (int*)ctrs);

  gemm_enc<<<dim3(NROWS / 256, HD / 128), dim3(512), 0, stream>>>(
      x_bf, encWT, h_bf, enc_b, NROWS, HD, DIN);

  gate_kernel<<<dim3(NROWS / 4), blk, 0, stream>>>(
      h_bf, gate_W, coef_W, coef_b, eidx, s0, c1, nflag, flags);

  fixup1_kernel<float><<<dim3(16, 16, F1Z), blk, 0, stream>>>(
      x, enc_W, flags, nflag, zpart, MAXFLAG, MAXFLAG);
  fixup2_kernel<0, float><<<dim3(128), blk, 0, stream>>>(
      zpart, enc_b, gate_W, coef_W, coef_b, flags, nflag, eidx, s0, c1,
      nflag2, flags2, MAXFLAG, MAXFLAG);
  fixup1_kernel<double><<<dim3(16, 16, F1Z), blk, 0, stream>>>(
      x, enc_W, flags2, nflag2, zpartB, MAXFLAG2, MAXFLAG2);
  fixup2_kernel<1, double><<<dim3(128), blk, 0, stream>>>(
      zpartB, enc_b, gate_W, coef_W, coef_b, flags2, nflag2, eidx, s0, c1,
      nullptr, nullptr, MAXFLAG2, MAXFLAG2);

  scan_scatter_kernel<<<dim3(1), dim3(1024), 0, stream>>>(
      eidx, tinfo, rowperm);

  gemm_moe<<<dim3(MAX_TILES, HD / 128), blk, 0, stream>>>(
      h_bf, expWT, accout, exp_b, rowperm, tinfo, s0, NROWS, HD, HD);
  gemm_mlp<<<dim3(NROWS / 256, HD / 128), dim3(512), 0, stream>>>(
      h_bf, mlpWT, accout, mlp_b, c1, NROWS, HD, HD);
  gemm_dec<<<dim3(NROWS / 256, DIN / 128), dim3(512), 0, stream>>>(
      accout, decWT, (float*)d_out, dec_b, NROWS, DIN, HD);
}

// Round 22
// 274.396 us; speedup vs baseline: 1.0122x; 1.0122x over previous
//
#include <hip/hip_runtime.h>
#include <hip/hip_bf16.h>
#include <stdint.h>

// ============================================================================
// MoE Autoencoder (N=8192, D_IN=2048, H=1024, E=8).  f32 in / f32 out,
// bf16-tolerance (0.0625) => bf16 MFMA compute.
// Round 22: revert to best-measured configuration (R19, 275.5us):
//   - prep: cast 8 elems/iter (CASTB=2048) + 64x64 transposes (3328 blocks)
//   - gemm8p: 2-deep counted-vmcnt pipeline, 4Mx2N wave grid, T2 swizzle
//   - moe: gathered 128x128 2-deep pipeline
// R20 prep-depth and R21 3-deep were nulls; plateau reached at ~275us.
// ============================================================================

using bf16 = __hip_bfloat16;
typedef __bf16 bf16x8 __attribute__((ext_vector_type(8)));
typedef float f32x4 __attribute__((ext_vector_type(4)));

static constexpr int NROWS = 8192;
static constexpr int DIN   = 2048;
static constexpr int HD    = 1024;
static constexpr int NEXP  = 8;
static constexpr int MAX_TILES = 72;
static constexpr int MAXFLAG  = 512;
static constexpr int MAXFLAG2 = 128;
static constexpr int F1Z = 7;
static constexpr int CASTB = 2048;
#define GAPTHR  0.02f
#define GAPTHR2 1.0e-3

__device__ __forceinline__ uint16_t f2u(float f) {
  bf16 h = __float2bfloat16(f);
  uint16_t u; __builtin_memcpy(&u, &h, 2); return u;
}
__device__ __forceinline__ float u2f(uint16_t u) {
  uint32_t x = ((uint32_t)u) << 16;
  float f; __builtin_memcpy(&f, &x, 4); return f;
}

typedef const __attribute__((address_space(1))) void* gas_ptr;
typedef __attribute__((address_space(3))) void* las_ptr;
__device__ __forceinline__ void async16(void* lds, const void* g) {
  __builtin_amdgcn_global_load_lds((gas_ptr)g, (las_ptr)lds, 16, 0, 0);
}

// ----------------------------------------------------------------------------
// prep: ctrs zero + x f32->bf16 cast + 4 weight transposes, one launch.
// ----------------------------------------------------------------------------
__global__ __launch_bounds__(256)
void prep_kernel(const float* __restrict__ x, uint16_t* __restrict__ x_bf,
                 const float* __restrict__ encW, uint16_t* __restrict__ encWT,
                 const float* __restrict__ mlpW, uint16_t* __restrict__ mlpWT,
                 const float* __restrict__ decW, uint16_t* __restrict__ decWT,
                 const float* __restrict__ expW, uint16_t* __restrict__ expWT,
                 int* __restrict__ ctrs_i)
{
  __shared__ float tile[64 * 65];
  const int b = blockIdx.x;
  const int t = threadIdx.x;
  if (b == 0 && t < 64) ctrs_i[t] = 0;

  if (b < CASTB) {                        // ---- x cast ----
    const int n8 = NROWS * DIN / 8;
    for (int i = b * 256 + t; i < n8; i += CASTB * 256) {
      const float* s = x + (size_t)i * 8;
      float4 v0 = *(const float4*)(s);
      float4 v1 = *(const float4*)(s + 4);
      uint16_t tmp[8];
      tmp[0]=f2u(v0.x); tmp[1]=f2u(v0.y); tmp[2]=f2u(v0.z); tmp[3]=f2u(v0.w);
      tmp[4]=f2u(v1.x); tmp[5]=f2u(v1.y); tmp[6]=f2u(v1.z); tmp[7]=f2u(v1.w);
      int4 pv; __builtin_memcpy(&pv, tmp, 16);
      *(int4*)(x_bf + (size_t)i * 8) = pv;
    }
    return;
  }
  const float* in; uint16_t* out; int R, C, bx, by;
  int q = b - CASTB;
  if (q < 512)       { in = encW; out = encWT; R = DIN; C = HD;  bx = q & 15; by = q >> 4; }
  else if (q < 768)  { q -= 512;  in = mlpW; out = mlpWT; R = HD; C = HD;  bx = q & 15; by = q >> 4; }
  else if (q < 1280) { q -= 768;  in = decW; out = decWT; R = HD; C = DIN; bx = q & 31; by = q >> 5; }
  else { q -= 1280; const int z = q >> 8; q &= 255;
         in = expW + (size_t)z * HD * HD; out = expWT + (size_t)z * HD * HD;
         R = HD; C = HD; bx = q & 15; by = q >> 4; }
  const int C0 = bx * 64, R0 = by * 64;
  const int cl = (t & 7) * 8;
#pragma unroll
  for (int p = 0; p < 2; ++p) {
    const int r = p * 32 + (t >> 3);
    const float* src = in + (size_t)(R0 + r) * C + C0 + cl;
    float4 v0 = *(const float4*)(src);
    float4 v1 = *(const float4*)(src + 4);
    float* dst = &tile[r * 65 + cl];
    dst[0]=v0.x; dst[1]=v0.y; dst[2]=v0.z; dst[3]=v0.w;
    dst[4]=v1.x; dst[5]=v1.y; dst[6]=v1.z; dst[7]=v1.w;
  }
  __syncthreads();
#pragma unroll
  for (int p = 0; p < 2; ++p) {
    const int oc = p * 32 + (t >> 3);
    uint16_t tmp[8];
#pragma unroll
    for (int j = 0; j < 8; ++j) tmp[j] = f2u(tile[(cl + j) * 65 + oc]);
    int4 v; __builtin_memcpy(&v, tmp, 16);
    *(int4*)(out + (size_t)(C0 + oc) * R + R0 + cl) = v;
  }
}

// ----------------------------------------------------------------------------
// Pipelined 256x128 GEMM, BK=64, 8 waves (4M x 2N, 64x64 each), T2+T3+T4+T5.
// MODE 0: enc  relu(acc+b) -> bf16;  MODE 2: mlp RMW;  MODE 3: dec f32 out.
// ----------------------------------------------------------------------------
template<int MODE>
__device__ __forceinline__
void gemm8p_body(const uint16_t* __restrict__ A, const uint16_t* __restrict__ BT,
                 uint16_t* __restrict__ C16, float* __restrict__ C32,
                 const float* __restrict__ biasf, const float* __restrict__ scale,
                 int M, int N, int K)
{
  constexpr int BM = 256, BN = 128, BK = 64;
  __shared__ uint16_t As[2][BM * BK];
  __shared__ uint16_t Bs[2][BN * BK];

  const int t = threadIdx.x;
  const int ntyg = gridDim.y;
  const int nwg  = gridDim.x * ntyg;
  const int hwf  = blockIdx.y * gridDim.x + blockIdx.x;
  const int swzb = (hwf & 7) * (nwg >> 3) + (hwf >> 3);
  const int mtile = swzb / ntyg;
  const int ntile = swzb % ntyg;

  const int trow = t >> 3;
  const int cbD  = (t & 7) * 16;
  const int cbS  = cbD ^ ((trow & 7) << 4);
  const char* aRow[4];
  const char* bRow[2];
#pragma unroll
  for (int c = 0; c < 4; ++c)
    aRow[c] = (const char*)A + ((size_t)(mtile * BM + c * 64 + trow) * K) * 2 + cbS;
#pragma unroll
  for (int c = 0; c < 2; ++c)
    bRow[c] = (const char*)BT + ((size_t)(ntile * BN + c * 64 + trow) * K) * 2 + cbS;

  auto stage = [&](int b, int kt) {
#pragma unroll
    for (int c = 0; c < 4; ++c)
      async16(&As[b][c * 4096 + t * 8], aRow[c] + (size_t)kt * 128);
#pragma unroll
    for (int c = 0; c < 2; ++c)
      async16(&Bs[b][c * 4096 + t * 8], bRow[c] + (size_t)kt * 128);
  };

  const int wid = t >> 6, lane = t & 63;
  const int wm = wid >> 1, wn = wid & 1;      // 4M x 2N wave grid, 64x64 each
  const int frow = lane & 15, hi = lane >> 4;

  f32x4 acc[4][4];
  const f32x4 zero = {0.f, 0.f, 0.f, 0.f};
#pragma unroll
  for (int i = 0; i < 4; ++i)
#pragma unroll
    for (int j = 0; j < 4; ++j) acc[i][j] = zero;

  auto ldfrag = [&](const uint16_t* base, int row, int kk) {
    const int cb = (kk * 64 + hi * 16) ^ ((row & 7) << 4);
    return *reinterpret_cast<const bf16x8*>(
        reinterpret_cast<const char*>(base) + row * 128 + cb);
  };

  const int nt = K >> 6;
  stage(0, 0);
  stage(1, 1);

  for (int kt = 0; kt < nt; ++kt) {
    const int b = kt & 1;
    asm volatile("s_waitcnt vmcnt(6)" ::: "memory");
    __builtin_amdgcn_s_barrier();

    bf16x8 af[4][2], bfr[4][2];
#pragma unroll
    for (int mi = 0; mi < 4; ++mi)
#pragma unroll
      for (int kk = 0; kk < 2; ++kk)
        af[mi][kk] = ldfrag(As[b], wm * 64 + mi * 16 + frow, kk);
#pragma unroll
    for (int ni = 0; ni < 4; ++ni)
#pragma unroll
      for (int kk = 0; kk < 2; ++kk)
        bfr[ni][kk] = ldfrag(Bs[b], wn * 64 + ni * 16 + frow, kk);

    asm volatile("s_waitcnt lgkmcnt(0)" ::: "memory");
    __builtin_amdgcn_s_barrier();

    if (kt + 2 < nt) stage(b, kt + 2);

    __builtin_amdgcn_s_setprio(1);
#pragma unroll
    for (int kk = 0; kk < 2; ++kk)
#pragma unroll
      for (int mi = 0; mi < 4; ++mi)
#pragma unroll
        for (int ni = 0; ni < 4; ++ni)
          acc[mi][ni] = __builtin_amdgcn_mfma_f32_16x16x32_bf16(
              af[mi][kk], bfr[ni][kk], acc[mi][ni], 0, 0, 0);
    __builtin_amdgcn_s_setprio(0);
  }

  // epilogue — C/D layout: col = lane&15, row = hi*4 + j   [m89]
  const int nbase = ntile * BN + wn * 64;
  const int rbase = mtile * BM + wm * 64 + hi * 4;
  const int cbase = lane & 15;
#pragma unroll
  for (int mi = 0; mi < 4; ++mi) {
#pragma unroll
    for (int j = 0; j < 4; ++j) {
      const int gr = rbase + mi * 16 + j;
#pragma unroll
      for (int ni = 0; ni < 4; ++ni) {
        const int gc = nbase + ni * 16 + cbase;
        float v = acc[mi][ni][j] + biasf[gc];
        if constexpr (MODE == 0) {
          C16[(size_t)gr * N + gc] = f2u(fmaxf(v, 0.f));
        } else if constexpr (MODE == 2) {
          const float prev = u2f(C16[(size_t)gr * N + gc]);
          C16[(size_t)gr * N + gc] = f2u(prev + v * scale[gr]);
        } else {
          C32[(size_t)gr * N + gc] = v;
        }
      }
    }
  }
}

__global__ __launch_bounds__(512)
void gemm_enc(const uint16_t* A, const uint16_t* BT, uint16_t* C16,
              const float* biasf, int M, int N, int K) {
  gemm8p_body<0>(A, BT, C16, nullptr, biasf, nullptr, M, N, K);
}
__global__ __launch_bounds__(512)
void gemm_mlp(const uint16_t* A, const uint16_t* BT, uint16_t* C16,
              const float* biasf, const float* scale, int M, int N, int K) {
  gemm8p_body<2>(A, BT, C16, nullptr, biasf, scale, M, N, K);
}
__global__ __launch_bounds__(512)
void gemm_dec(const uint16_t* A, const uint16_t* BT, float* C32,
              const float* biasf, int M, int N, int K) {
  gemm8p_body<3>(A, BT, nullptr, C32, biasf, nullptr, M, N, K);
}

// ----------------------------------------------------------------------------
// moe GEMM: gathered 128x128 tiles with counted-vmcnt 2-deep pipeline.
// ----------------------------------------------------------------------------
__global__ __launch_bounds__(256)
void gemm_moe(const uint16_t* __restrict__ A, const uint16_t* __restrict__ BT,
              uint16_t* __restrict__ C16, const float* __restrict__ biasf,
              const int* __restrict__ rowperm, const int* __restrict__ tinfo,
              const float* __restrict__ scale, int M, int N, int K)
{
  __shared__ uint16_t As[2][128 * 64];
  __shared__ uint16_t Bs[2][128 * 64];

  const int t = threadIdx.x;
  const int nty = gridDim.y;
  const int nwg = gridDim.x * nty;
  const int hwf = blockIdx.y * gridDim.x + blockIdx.x;
  const int swz = (hwf & 7) * (nwg >> 3) + (hwf >> 3);
  const int mtile = swz / nty;
  const int ntile = swz % nty;

  const int nt2 = tinfo[0];
  if (mtile >= nt2) return;
  const int e      = tinfo[1 + mtile * 3 + 0];
  const int row0   = tinfo[1 + mtile * 3 + 1];
  const int rowend = tinfo[1 + mtile * 3 + 2];

  const int trow = t >> 3;
  const int cbD  = (t & 7) * 16;
  const int cbS  = cbD ^ ((trow & 7) << 4);
  const char* asrc[4];
  const char* bsrc[4];
#pragma unroll
  for (int c = 0; c < 4; ++c) {
    const int r = c * 32 + trow;
    int pr = row0 + r;
    if (pr > rowend - 1) pr = rowend - 1;
    asrc[c] = (const char*)A + ((size_t)rowperm[pr] * K) * 2 + cbS;
    bsrc[c] = (const char*)BT + (((size_t)e * N + ntile * 128 + r) * K) * 2 + cbS;
  }

  auto stage = [&](int b, int kt) {
#pragma unroll
    for (int c = 0; c < 4; ++c) {
      async16(&As[b][c * 2048 + t * 8], asrc[c] + (size_t)kt * 128);
      async16(&Bs[b][c * 2048 + t * 8], bsrc[c] + (size_t)kt * 128);
    }
  };

  f32x4 acc[4][4];
  const f32x4 zero = {0.f, 0.f, 0.f, 0.f};
#pragma unroll
  for (int i = 0; i < 4; ++i)
#pragma unroll
    for (int j = 0; j < 4; ++j) acc[i][j] = zero;

  const int wid = t >> 6, lane = t & 63;
  const int wm = wid >> 1, wn = wid & 1;
  const int frow = lane & 15, hi = lane >> 4;

  auto ldfrag = [&](const uint16_t* base, int row, int kk) {
    const int cb = (kk * 64 + hi * 16) ^ ((row & 7) << 4);
    return *reinterpret_cast<const bf16x8*>(
        reinterpret_cast<const char*>(base) + row * 128 + cb);
  };

  const int nk = K >> 6;
  stage(0, 0);
  stage(1, 1);

  for (int kt = 0; kt < nk; ++kt) {
    const int b = kt & 1;
    asm volatile("s_waitcnt vmcnt(8)" ::: "memory");
    __builtin_amdgcn_s_barrier();

    bf16x8 af[4][2], bfr[4][2];
#pragma unroll
    for (int mi = 0; mi < 4; ++mi)
#pragma unroll
      for (int kk = 0; kk < 2; ++kk)
        af[mi][kk] = ldfrag(As[b], wm * 64 + mi * 16 + frow, kk);
#pragma unroll
    for (int ni = 0; ni < 4; ++ni)
#pragma unroll
      for (int kk = 0; kk < 2; ++kk)
        bfr[ni][kk] = ldfrag(Bs[b], wn * 64 + ni * 16 + frow, kk);

    asm volatile("s_waitcnt lgkmcnt(0)" ::: "memory");
    __builtin_amdgcn_s_barrier();

    if (kt + 2 < nk) stage(b, kt + 2);

    __builtin_amdgcn_s_setprio(1);
#pragma unroll
    for (int kk = 0; kk < 2; ++kk)
#pragma unroll
      for (int mi = 0; mi < 4; ++mi)
#pragma unroll
        for (int ni = 0; ni < 4; ++ni)
          acc[mi][ni] = __builtin_amdgcn_mfma_f32_16x16x32_bf16(
              af[mi][kk], bfr[ni][kk], acc[mi][ni], 0, 0, 0);
    __builtin_amdgcn_s_setprio(0);
  }

  const int nbase = ntile * 128 + wn * 64;
  const int rbase = wm * 64 + hi * 4;
  const int cbase = lane & 15;
#pragma unroll
  for (int mi = 0; mi < 4; ++mi) {
#pragma unroll
    for (int j = 0; j < 4; ++j) {
      const int pr = row0 + rbase + mi * 16 + j;
      if (pr < rowend) {
        const int orig = rowperm[pr];
        const float sc = scale[orig];
        uint16_t* dst = C16 + (size_t)orig * N;
#pragma unroll
        for (int ni = 0; ni < 4; ++ni) {
          const int gc = nbase + ni * 16 + cbase;
          dst[gc] = f2u((acc[mi][ni][j] + biasf[e * N + gc]) * sc);
        }
      }
    }
  }
}

// ----------------------------------------------------------------------------
// Gate from bf16 h — coalesced, no count atomic.
// ----------------------------------------------------------------------------
__global__ __launch_bounds__(256)
void gate_kernel(const uint16_t* __restrict__ hbf, const float* __restrict__ gW,
                 const float* __restrict__ cW, const float* __restrict__ cb,
                 int* __restrict__ eidx, float* __restrict__ s0,
                 float* __restrict__ c1, int* __restrict__ nflag,
                 int* __restrict__ flaglist)
{
  const int lane = threadIdx.x & 63;
  const int row  = blockIdx.x * 4 + (threadIdx.x >> 6);
  const uint16_t* hrow = hbf + (size_t)row * HD;
  float a[10];
#pragma unroll
  for (int i = 0; i < 10; ++i) a[i] = 0.f;
  for (int kk = 0; kk < HD / 64; ++kk) {
    const int k = kk * 64 + lane;
    const float hv = u2f(hrow[k]);
    float4 g0 = *(const float4*)(gW + (size_t)k * 8);
    float4 g1 = *(const float4*)(gW + (size_t)k * 8 + 4);
    a[0] += hv * g0.x; a[1] += hv * g0.y; a[2] += hv * g0.z; a[3] += hv * g0.w;
    a[4] += hv * g1.x; a[5] += hv * g1.y; a[6] += hv * g1.z; a[7] += hv * g1.w;
    float2 cv = *(const float2*)(cW + (size_t)k * 2);
    a[8] += hv * cv.x; a[9] += hv * cv.y;
  }
#pragma unroll
  for (int off = 32; off > 0; off >>= 1) {
#pragma unroll
    for (int i = 0; i < 10; ++i) a[i] += __shfl_xor(a[i], off);
  }
  if (lane == 0) {
    int best = 0; float bm = a[0];
#pragma unroll
    for (int e2 = 1; e2 < 8; ++e2) if (a[e2] > bm) { bm = a[e2]; best = e2; }
    float sec = -3.0e38f;
#pragma unroll
    for (int e2 = 0; e2 < 8; ++e2) if (e2 != best) sec = fmaxf(sec, a[e2]);
    float s = 0.f;
#pragma unroll
    for (int e2 = 0; e2 < 8; ++e2) s += expf(a[e2] - bm);
    const float p  = 1.f / s;
    const float l0 = a[8] + cb[0], l1 = a[9] + cb[1];
    const float mx = fmaxf(l0, l1);
    const float e0 = expf(l0 - mx), e1 = expf(l1 - mx);
    const float inv = 1.f / (e0 + e1);
    eidx[row] = best;
    s0[row]   = p * (e0 * inv);
    c1[row]   = e1 * inv;
    if (bm - sec < GAPTHR) {
      int fi = atomicAdd(nflag, 1);
      if (fi < MAXFLAG) flaglist[fi] = row;
    }
  }
}

// ----------------------------------------------------------------------------
// fixup1<T>
// ----------------------------------------------------------------------------
template<typename T>
__global__ __launch_bounds__(256)
void fixup1_kernel(const float* __restrict__ x, const float* __restrict__ encW,
                   const int* __restrict__ flaglist, const int* __restrict__ nflag,
                   T* __restrict__ zpart, int fstride, int maxflag)
{
  __shared__ float xs[8][128];
  __shared__ T red[8][4][64];
  int nf = *nflag; if (nf > maxflag) nf = maxflag;
  if (nf <= 0) return;
  const int rs = blockIdx.z;
  const int nb = (nf + 7) >> 3;
  if (rs >= nb) return;
  const int t  = threadIdx.x;
  const int jb = blockIdx.x, kb = blockIdx.y;
  const int tj = t & 63, tk = t >> 6;
  const int j  = jb * 64 + tj;
  const int k0 = kb * 128 + tk * 32;
  float w[32];
#pragma unroll
  for (int kk = 0; kk < 32; ++kk)
    w[kk] = encW[(size_t)(k0 + kk) * HD + j];

  for (int fb = rs; fb < nb; fb += F1Z) {
    __syncthreads();
    {
      const int r  = t >> 5;
      const int kc = (t & 31) * 4;
      int f = fb * 8 + r; if (f > nf - 1) f = nf - 1;
      const int row = flaglist[f];
      *(float4*)&xs[r][kc] =
          *(const float4*)&x[(size_t)row * DIN + kb * 128 + kc];
    }
    __syncthreads();
    T acc[8];
#pragma unroll
    for (int r = 0; r < 8; ++r) acc[r] = (T)0;
#pragma unroll
    for (int kq = 0; kq < 8; ++kq) {
      float4 xv[8];
#pragma unroll
      for (int r = 0; r < 8; ++r)
        xv[r] = *(const float4*)&xs[r][tk * 32 + kq * 4];
#pragma unroll
      for (int r = 0; r < 8; ++r) {
        acc[r] += (T)xv[r].x * (T)w[kq * 4 + 0];
        acc[r] += (T)xv[r].y * (T)w[kq * 4 + 1];
        acc[r] += (T)xv[r].z * (T)w[kq * 4 + 2];
        acc[r] += (T)xv[r].w * (T)w[kq * 4 + 3];
      }
    }
#pragma unroll
    for (int r = 0; r < 8; ++r) red[r][tk][tj] = acc[r];
    __syncthreads();
#pragma unroll
    for (int p = 0; p < 2; ++p) {
      const int idx = p * 256 + t;
      const int r = idx >> 6, jj = idx & 63;
      const int f = fb * 8 + r;
      if (f < nf)
        zpart[((size_t)kb * fstride + f) * HD + jb * 64 + jj] =
            (red[r][0][jj] + red[r][1][jj]) + (red[r][2][jj] + red[r][3][jj]);
    }
  }
}

// ----------------------------------------------------------------------------
// fixup2<STAGE,T>
// ----------------------------------------------------------------------------
template<int STAGE, typename T>
__global__ __launch_bounds__(256)
void fixup2_kernel(const T* __restrict__ zpart, const float* __restrict__ encB,
                   const float* __restrict__ gW, const float* __restrict__ cW,
                   const float* __restrict__ cb, const int* __restrict__ flaglist,
                   const int* __restrict__ nflag, int* __restrict__ eidx,
                   float* __restrict__ s0, float* __restrict__ c1,
                   int* __restrict__ nflag2, int* __restrict__ flaglist2,
                   int fstride, int maxflag)
{
  __shared__ double red[4][10];
  int nf = *nflag; if (nf > maxflag) nf = maxflag;
  const int t = threadIdx.x, lane = t & 63, w = t >> 6;
  for (int f = blockIdx.x; f < nf; f += 128) {
    const int row = flaglist[f];
    double part[10];
#pragma unroll
    for (int i = 0; i < 10; ++i) part[i] = 0.0;
    for (int jj = t; jj < HD; jj += 256) {
      double z = 0.0;
#pragma unroll
      for (int kb = 0; kb < 16; ++kb)
        z += (double)zpart[((size_t)kb * fstride + f) * HD + jj];
      double hj = z + (double)encB[jj];
      hj = hj > 0.0 ? hj : 0.0;
      const float* gr = gW + (size_t)jj * 8;
#pragma unroll
      for (int e2 = 0; e2 < 8; ++e2) part[e2] += hj * (double)gr[e2];
      part[8] += hj * (double)cW[jj * 2];
      part[9] += hj * (double)cW[jj * 2 + 1];
    }
#pragma unroll
    for (int off = 32; off > 0; off >>= 1)
#pragma unroll
      for (int i = 0; i < 10; ++i) part[i] += __shfl_xor(part[i], off);
    if (lane == 0)
#pragma unroll
      for (int i = 0; i < 10; ++i) red[w][i] = part[i];
    __syncthreads();
    if (t == 0) {
      double a[10];
#pragma unroll
      for (int i = 0; i < 10; ++i)
        a[i] = red[0][i] + red[1][i] + red[2][i] + red[3][i];
      int best = 0; double bm = a[0];
#pragma unroll
      for (int e2 = 1; e2 < 8; ++e2) if (a[e2] > bm) { bm = a[e2]; best = e2; }
      double sec = -1.0e300;
#pragma unroll
      for (int e2 = 0; e2 < 8; ++e2) if (e2 != best && a[e2] > sec) sec = a[e2];
      double s = 0.0;
#pragma unroll
      for (int e2 = 0; e2 < 8; ++e2) s += exp(a[e2] - bm);
      const double p  = 1.0 / s;
      const double l0 = a[8] + (double)cb[0], l1 = a[9] + (double)cb[1];
      const double mx = l0 > l1 ? l0 : l1;
      const double e0 = exp(l0 - mx), e1 = exp(l1 - mx);
      const double inv = 1.0 / (e0 + e1);
      eidx[row] = best;
      s0[row]   = (float)(p * e0 * inv);
      c1[row]   = (float)(e1 * inv);
      if constexpr (STAGE == 0) {
        if (bm - sec < GAPTHR2) {
          int fi = atomicAdd(nflag2, 1);
          if (fi < MAXFLAG2) flaglist2[fi] = row;
        }
      }
    }
    __syncthreads();
  }
}

// ----------------------------------------------------------------------------
// scan + scatter + count, single block (LDS histogram).
// ----------------------------------------------------------------------------
__global__ __launch_bounds__(1024)
void scan_scatter_kernel(const int* __restrict__ eidx,
                         int* __restrict__ tinfo, int* __restrict__ rowperm)
{
  __shared__ int scnt[NEXP];
  __shared__ int soffs[NEXP];
  __shared__ int scur[NEXP];
  const int t = threadIdx.x;
  if (t < NEXP) scnt[t] = 0;
  __syncthreads();
  for (int n = t; n < NROWS; n += 1024)
    atomicAdd(&scnt[eidx[n]], 1);
  __syncthreads();
  if (t == 0) {
    int off = 0, nt = 0;
    for (int e = 0; e < NEXP; ++e) {
      soffs[e] = off; scur[e] = 0;
      const int c = scnt[e];
      const int end = off + c;
      for (int r = 0; r < c; r += 128) {
        tinfo[1 + nt * 3 + 0] = e;
        tinfo[1 + nt * 3 + 1] = off + r;
        tinfo[1 + nt * 3 + 2] = end;
        ++nt;
      }
      off = end;
    }
    tinfo[0] = nt;
  }
  __syncthreads();
  for (int n = t; n < NROWS; n += 1024) {
    const int e = eidx[n];
    rowperm[soffs[e] + atomicAdd(&scur[e], 1)] = n;
  }
}

// ----------------------------------------------------------------------------
extern "C" void kernel_launch(void* const* d_in, const int* in_sizes, int n_in,
                              void* d_out, int out_size, void* d_ws, size_t ws_size,
                              hipStream_t stream) {
  (void)in_sizes; (void)n_in; (void)out_size;
  const float* x      = (const float*)d_in[0];
  const float* enc_W  = (const float*)d_in[1];
  const float* enc_b  = (const float*)d_in[2];
  const float* gate_W = (const float*)d_in[3];
  const float* exp_W  = (const float*)d_in[4];
  const float* exp_b  = (const float*)d_in[5];
  const float* mlp_W  = (const float*)d_in[6];
  const float* mlp_b  = (const float*)d_in[7];
  const float* coef_W = (const float*)d_in[8];
  const float* coef_b = (const float*)d_in[9];
  const float* dec_W  = (const float*)d_in[10];
  const float* dec_b  = (const float*)d_in[11];

  char* ws = (char*)d_ws;
  size_t off = 0;
  auto alloc = [&](size_t bytes) {
    char* p = ws + off;
    off += (bytes + 255) & ~(size_t)255;
    return p;
  };
  uint16_t* encWT  = (uint16_t*)alloc((size_t)DIN * HD * 2);
  uint16_t* mlpWT  = (uint16_t*)alloc((size_t)HD * HD * 2);
  uint16_t* decWT  = (uint16_t*)alloc((size_t)HD * DIN * 2);
  uint16_t* expWT  = (uint16_t*)alloc((size_t)NEXP * HD * HD * 2);
  uint16_t* h_bf   = (uint16_t*)alloc((size_t)NROWS * HD * 2);
  float*    zpart  = (float*)   alloc((size_t)16 * MAXFLAG * HD * 4);
  int*      eidx   = (int*)     alloc(NROWS * 4);
  float*    s0     = (float*)   alloc(NROWS * 4);
  float*    c1     = (float*)   alloc(NROWS * 4);
  int*      rowperm= (int*)     alloc(NROWS * 4);
  int*      flags  = (int*)     alloc(MAXFLAG * 4);
  int*      flags2 = (int*)     alloc(MAXFLAG2 * 4);
  char*     ctrs   = (char*)    alloc(256);
  int*      tinfo  = (int*)     alloc((1 + MAX_TILES * 3) * 4 + 64);
  uint16_t* x_bf   = (uint16_t*)zpart;   // lifetime-disjoint aliases (see R14)
  double*   zpartB = (double*)zpart;
  uint16_t* accout = (uint16_t*)zpart;
  int*      nflag  = (int*)(ctrs + 32);
  int*      nflag2 = (int*)(ctrs + 64);
  if (off > ws_size) return;

  const dim3 blk(256);
  prep_kernel<<<dim3(CASTB + 3328), blk, 0, stream>>>(
      x, x_bf, enc_W, encWT, mlp_W, mlpWT, dec_W, decWT, exp_W, expWT,
      (int*)ctrs);

  gemm_enc<<<dim3(NROWS / 256, HD / 128), dim3(512), 0, stream>>>(
      x_bf, encWT, h_bf, enc_b, NROWS, HD, DIN);

  gate_kernel<<<dim3(NROWS / 4), blk, 0, stream>>>(
      h_bf, gate_W, coef_W, coef_b, eidx, s0, c1, nflag, flags);

  fixup1_kernel<float><<<dim3(16, 16, F1Z), blk, 0, stream>>>(
      x, enc_W, flags, nflag, zpart, MAXFLAG, MAXFLAG);
  fixup2_kernel<0, float><<<dim3(128), blk, 0, stream>>>(
      zpart, enc_b, gate_W, coef_W, coef_b, flags, nflag, eidx, s0, c1,
      nflag2, flags2, MAXFLAG, MAXFLAG);
  fixup1_kernel<double><<<dim3(16, 16, F1Z), blk, 0, stream>>>(
      x, enc_W, flags2, nflag2, zpartB, MAXFLAG2, MAXFLAG2);
  fixup2_kernel<1, double><<<dim3(128), blk, 0, stream>>>(
      zpartB, enc_b, gate_W, coef_W, coef_b, flags2, nflag2, eidx, s0, c1,
      nullptr, nullptr, MAXFLAG2, MAXFLAG2);

  scan_scatter_kernel<<<dim3(1), dim3(1024), 0, stream>>>(
      eidx, tinfo, rowperm);

  gemm_moe<<<dim3(MAX_TILES, HD / 128), blk, 0, stream>>>(
      h_bf, expWT, accout, exp_b, rowperm, tinfo, s0, NROWS, HD, HD);
  gemm_mlp<<<dim3(NROWS / 256, HD / 128), dim3(512), 0, stream>>>(
      h_bf, mlpWT, accout, mlp_b, c1, NROWS, HD, HD);
  gemm_dec<<<dim3(NROWS / 256, DIN / 128), dim3(512), 0, stream>>>(
      accout, decWT, (float*)d_out, dec_b, NROWS, DIN, HD);
}